// Round 3
// 85.587 us; speedup vs baseline: 1.0151x; 1.0151x over previous
//
#include <hip/hip_runtime.h>
#include <math.h>

#define B_  4
#define P_  512
#define K_  4
#define H_  200
#define W_  336
#define A_  14
#define PS_ 56
#define SCALE_ 0.25f
#define HW_    (H_ * W_)
#define PXB_   16                // bytes per ws pixel
#define ROWB_  (W_ * PXB_)       // 5376
#define PLB_   (HW_ * PXB_)      // bytes per (b) plane
#define RROWB_ (PS_ * K_ * 4)    // bytes per smR row (= 896)

#if __has_builtin(__builtin_amdgcn_exp2f)
#define EXP2F(x) __builtin_amdgcn_exp2f(x)
#else
#define EXP2F(x) exp2f(x)
#endif

typedef _Float16 h2 __attribute__((ext_vector_type(2)));

static __device__ __forceinline__ unsigned pkrtz_u(float a, float b) {
    auto h = __builtin_amdgcn_cvt_pkrtz(a, b);
    union { decltype(h) h; unsigned u; } c; c.h = h; return c.u;
}
static __device__ __forceinline__ h2 u2h(unsigned u) {
    union { unsigned u; h2 h; } c; c.u = u; return c.h;
}
static __device__ __forceinline__ float dot2(h2 a, h2 b, float c) {
#if __has_builtin(__builtin_amdgcn_fdot2)
    return __builtin_amdgcn_fdot2(a, b, c, false);
#else
    return (float)a.x * (float)b.x + ((float)a.y * (float)b.y + c);
#endif
}
static __device__ __forceinline__ uint4 ld16(const char* p) {
    uint4 q;
    __builtin_memcpy(&q, (const char*)__builtin_assume_aligned(p, 16), 16);
    return q;
}

// ---- Pass 1: bases [B,K,H,W] -> ws [B,H,W] = f16 {k:(x,x+1)} x4 (16B/pixel) ----
__global__ __launch_bounds__(256) void transpose_bases(
    const float* __restrict__ bases, uint4* __restrict__ ws)
{
    const int i = blockIdx.x * 256 + threadIdx.x;    // over B*H*W = 268800
    if (i >= B_ * HW_) return;
    const int b = i / HW_;
    const int r = i - b * HW_;
    const int x = r % W_;
    const int dn = (x < W_ - 1) ? 1 : 0;             // duplicate last column
    const float* src = bases + (size_t)b * (K_ * HW_) + r;
    uint4 w;
    w.x = pkrtz_u(src[0 * HW_], src[0 * HW_ + dn]);
    w.y = pkrtz_u(src[1 * HW_], src[1 * HW_ + dn]);
    w.z = pkrtz_u(src[2 * HW_], src[2 * HW_ + dn]);
    w.w = pkrtz_u(src[3 * HW_], src[3 * HW_ + dn]);
    ws[i] = w;
}

// ---- Pass 2: main blender — 256 thr/block, 8 blocks/CU, single dispatch round ----
__global__ __launch_bounds__(256, 8) void blender_kernel(
    const uint4* __restrict__ wsb,     // [B,H,W] f16 pair-duplicated bases
    const float* __restrict__ boxes,   // [B,P,4]
    const float* __restrict__ attn,    // [B,P,K,A,A]
    float* __restrict__ out)           // [B,P,PS,PS]
{
    const int tid = threadIdx.x;       // 256 threads, 4 waves
    const int bp  = blockIdx.x;
    const int b   = bp >> 9;           // / 512

    __shared__ alignas(16) float  smTile[K_ * A_ * A_]; // attn tile, pre-scaled by log2e
    __shared__ alignas(16) float  smR[A_ * PS_ * K_];   // x-interp attn*log2e, [ay][px][k]
    __shared__ alignas(16) float2 smX[PS_];             // {asint(x0*16), asuint(wx h2)}
    __shared__ alignas(16) float2 smTx[PS_];            // {tx, asint(ix0*4)}
    __shared__ alignas(16) float4 smY[PS_];             // {asint(y0*ROWB), o_dy|(ayo<<16), pk(wy0,wy1), ty}

    const float LOG2E = 1.4426950408889634f;

    // ---- stage attn tile (pre-scaled: lerp is linear, fold log2e here) ----
    const float* ap = attn + (size_t)bp * (K_ * A_ * A_);
    for (int i = tid; i < K_ * A_ * A_; i += 256)
        smTile[i] = __builtin_nontemporal_load(ap + i) * LOG2E;

    // ---- separable tables ----
    const float* bx = boxes + (size_t)bp * 4;
    const float rr = 13.0f / 55.0f;            // (A-1)/(PS-1)

    if (tid < PS_) {                           // x-side
        const int px = tid;
        const float x1 = bx[0] * SCALE_;
        const float x2 = bx[2] * SCALE_;
        const float bw = fmaxf(x2 - x1, 1.0f) * (1.0f / PS_);
        const float sx = x1 + (px + 0.5f) * bw;
        const float vx = (sx > -1.0f && sx < (float)W_) ? 1.0f : 0.0f;
        const float cx = fminf(fmaxf(sx, 0.0f), (float)(W_ - 1));
        const int   x0 = (int)cx;
        const float lx = cx - (float)x0;       // x0==W-1 -> lx==0, dup col absorbs
        float2 v;
        v.x = __int_as_float(x0 * PXB_);
        v.y = __uint_as_float(pkrtz_u((1.0f - lx) * vx, lx * vx));
        smX[px] = v;
        // box-independent x-lerp table for the smR fill
        const float srcx = (float)px * rr;
        const int ix0 = min((int)srcx, A_ - 2);
        float2 t;
        t.x = srcx - (float)ix0;
        t.y = __int_as_float(ix0 * 4);         // byte offset within tile row
        smTx[px] = t;
    } else if (tid >= 64 && tid < 64 + PS_) {  // y-side
        const int py = tid - 64;
        const float y1 = bx[1] * SCALE_;
        const float y2 = bx[3] * SCALE_;
        const float bh = fmaxf(y2 - y1, 1.0f) * (1.0f / PS_);
        const float sy = y1 + (py + 0.5f) * bh;
        const float vy = (sy > -1.0f && sy < (float)H_) ? 1.0f : 0.0f;
        const float cy = fminf(fmaxf(sy, 0.0f), (float)(H_ - 1));
        const int   y0 = (int)cy;
        const int   y1i = min(y0 + 1, H_ - 1);
        const float ly = cy - (float)y0;
        const float wy0 = (1.0f - ly) * vy;
        const float wy1 = ly * vy;
        const float srcy = (float)py * rr;
        const int iy0 = min((int)srcy, A_ - 2);
        const unsigned odp = (unsigned)((y1i - y0) * ROWB_)     // 13 bits
                           | ((unsigned)(iy0 * RROWB_) << 16);  // 14 bits
        float4 v;
        v.x = __int_as_float(y0 * ROWB_);
        v.y = __uint_as_float(odp);
        v.z = __uint_as_float(pkrtz_u(wy0, wy1));
        v.w = srcy - (float)iy0;               // ty, fp32
        smY[py] = v;
    }
    __syncthreads();

    // ---- x-interp attn -> smR[ay][px][k]: 784 items, k-vectorized body ----
    // (one magic divide + 4 paired LDS reads + 4 fma + one b128 write per item,
    //  vs. the old 3136-item loop with per-item index math)
    for (int i = tid; i < A_ * PS_; i += 256) {             // i = ay*56 + px
        const int ay = (int)(((unsigned)i * 37450u) >> 21); // i/56
        const int px = i - ay * PS_;
        const float2 T = smTx[px];
        const float tx = T.x;
        const int  ixo = __float_as_int(T.y);
        const float* t0 = (const float*)((const char*)smTile + ay * (A_ * 4) + ixo);
        const float* t1 = t0 + A_ * A_;
        const float* t2 = t0 + 2 * A_ * A_;
        const float* t3 = t0 + 3 * A_ * A_;
        float4 o;
        o.x = fmaf(tx, t0[1] - t0[0], t0[0]);
        o.y = fmaf(tx, t1[1] - t1[0], t1[0]);
        o.z = fmaf(tx, t2[1] - t2[0], t2[0]);
        o.w = fmaf(tx, t3[1] - t3[0], t3[0]);
        *(float4*)&smR[i * K_] = o;
    }
    __syncthreads();

    // ---- main loop: idx = tid + 256*t, t = 0..11 (+64 tail); 2-slot pipeline ----
    const char* fb = (const char*)wsb + (size_t)b * PLB_;
    float* outp = out + (size_t)bp * (PS_ * PS_);
    const char* smRc = (const char*)smR;

    // initial px/py for idx = tid  (py = idx/56 via magic, px = rem)
    int py = (int)(((unsigned)tid * 37450u) >> 21);
    int px = tid - py * PS_;

    struct PState {
        uint4 q0, q1;
        unsigned wxu, wyu;
        float ty;
        int   ayo, pxo;
    };

    // issue for current (px,py), then advance (px,py) by 256 linear
    auto issue = [&](PState& S) {
        const int pyc = min(py, PS_ - 1);      // clamp: speculative tail prefetch
        const float2 X = smX[px];
        const float4 Y = smY[pyc];
        const unsigned w1 = __float_as_uint(Y.y);
        const unsigned o0 = (unsigned)__float_as_int(Y.x) + (unsigned)__float_as_int(X.x);
        const unsigned o1 = o0 + (w1 & 0xffffu);
        S.q0 = ld16(fb + o0);
        S.q1 = ld16(fb + o1);
        S.wxu = __float_as_uint(X.y);
        S.wyu = __float_as_uint(Y.z);
        S.ty  = Y.w;
        S.ayo = (int)(w1 >> 16);
        S.pxo = px << 4;
        px += 32; py += 4;
        if (px >= PS_) { px -= PS_; py += 1; }
    };

    auto compute = [&](const PState& S) -> float {
        const h2 wx  = u2h(S.wxu);
        const h2 wyp = u2h(S.wyu);             // {wy0, wy1}
        const h2 wy0b = {wyp.x, wyp.x};        // op_sel broadcast
        const h2 wy1b = {wyp.y, wyp.y};
        const h2 wxy0 = wx * wy0b;             // v_pk_mul_f16
        const h2 wxy1 = wx * wy1b;
        const float v0 = dot2(u2h(S.q1.x), wxy1, dot2(u2h(S.q0.x), wxy0, 0.0f));
        const float v1 = dot2(u2h(S.q1.y), wxy1, dot2(u2h(S.q0.y), wxy0, 0.0f));
        const float v2 = dot2(u2h(S.q1.z), wxy1, dot2(u2h(S.q0.z), wxy0, 0.0f));
        const float v3 = dot2(u2h(S.q1.w), wxy1, dot2(u2h(S.q0.w), wxy0, 0.0f));

        const char* rb = smRc + S.pxo + S.ayo;
        const float4 a0v = *(const float4*)(rb);
        const float4 a1v = *(const float4*)(rb + RROWB_);
        const float ty = S.ty;
        const float e0 = EXP2F(fmaf(ty, a1v.x - a0v.x, a0v.x));
        const float e1 = EXP2F(fmaf(ty, a1v.y - a0v.y, a0v.y));
        const float e2 = EXP2F(fmaf(ty, a1v.z - a0v.z, a0v.z));
        const float e3 = EXP2F(fmaf(ty, a1v.w - a0v.w, a0v.w));

        const float s = (e0 + e1) + (e2 + e3);
        float acc = e0 * v0;
        acc = fmaf(e1, v1, acc);
        acc = fmaf(e2, v2, acc);
        acc = fmaf(e3, v3, acc);
        return acc * __builtin_amdgcn_rcpf(s);
    };

    PState SA, SB;
    issue(SA);
    #pragma unroll
    for (int g = 0; g < 12; g += 2) {
        issue(SB);
        __builtin_nontemporal_store(compute(SA), outp + tid + 256 * g);
        issue(SA);                              // g=10 -> prefetches tail (clamped)
        __builtin_nontemporal_store(compute(SB), outp + tid + 256 * (g + 1));
    }
    if (tid < 64)                               // tail: idx = 3072 + tid
        __builtin_nontemporal_store(compute(SA), outp + tid + 256 * 12);
}

extern "C" void kernel_launch(void* const* d_in, const int* in_sizes, int n_in,
                              void* d_out, int out_size, void* d_ws, size_t ws_size,
                              hipStream_t stream) {
    const float* bases = (const float*)d_in[0];  // [B,K,H,W]
    const float* boxes = (const float*)d_in[1];  // [B,P,4]
    const float* attn  = (const float*)d_in[2];  // [B,P,K,A,A]
    float* out = (float*)d_out;                  // [B,P,PS,PS]
    uint4* wsb = (uint4*)d_ws;                   // 268800 * 16 B = 4.3 MB scratch

    transpose_bases<<<dim3((B_ * HW_ + 255) / 256), dim3(256), 0, stream>>>(bases, wsb);
    blender_kernel<<<dim3(B_ * P_), dim3(256), 0, stream>>>(wsb, boxes, attn, out);
}

// Round 4
// 83.902 us; speedup vs baseline: 1.0355x; 1.0201x over previous
//
#include <hip/hip_runtime.h>
#include <math.h>

#define B_  4
#define P_  512
#define K_  4
#define H_  200
#define W_  336
#define A_  14
#define PS_ 56
#define SCALE_ 0.25f
#define HW_    (H_ * W_)
#define PXB_   16                // bytes per ws pixel
#define ROWB_  (W_ * PXB_)       // 5376
#define PLB_   (HW_ * PXB_)      // bytes per (b) plane
#define RROWB_ (PS_ * K_ * 4)    // bytes per smR row (= 896)

#if __has_builtin(__builtin_amdgcn_exp2f)
#define EXP2F(x) __builtin_amdgcn_exp2f(x)
#else
#define EXP2F(x) exp2f(x)
#endif

typedef _Float16 h2 __attribute__((ext_vector_type(2)));

static __device__ __forceinline__ unsigned pkrtz_u(float a, float b) {
    auto h = __builtin_amdgcn_cvt_pkrtz(a, b);
    union { decltype(h) h; unsigned u; } c; c.h = h; return c.u;
}
static __device__ __forceinline__ h2 u2h(unsigned u) {
    union { unsigned u; h2 h; } c; c.u = u; return c.h;
}
static __device__ __forceinline__ float dot2(h2 a, h2 b, float c) {
#if __has_builtin(__builtin_amdgcn_fdot2)
    return __builtin_amdgcn_fdot2(a, b, c, false);
#else
    return (float)a.x * (float)b.x + ((float)a.y * (float)b.y + c);
#endif
}
static __device__ __forceinline__ uint4 ld16(const char* p) {
    uint4 q;
    __builtin_memcpy(&q, (const char*)__builtin_assume_aligned(p, 16), 16);
    return q;
}

// ---- Pass 1: bases [B,K,H,W] -> ws [B,H,W] = f16 {k:(x,x+1)} x4 (16B/pixel) ----
__global__ __launch_bounds__(256) void transpose_bases(
    const float* __restrict__ bases, uint4* __restrict__ ws)
{
    const int i = blockIdx.x * 256 + threadIdx.x;    // over B*H*W = 268800
    if (i >= B_ * HW_) return;
    const int b = i / HW_;
    const int r = i - b * HW_;
    const int x = r % W_;
    const int dn = (x < W_ - 1) ? 1 : 0;             // duplicate last column
    const float* src = bases + (size_t)b * (K_ * HW_) + r;
    uint4 w;
    w.x = pkrtz_u(src[0 * HW_], src[0 * HW_ + dn]);
    w.y = pkrtz_u(src[1 * HW_], src[1 * HW_ + dn]);
    w.z = pkrtz_u(src[2 * HW_], src[2 * HW_ + dn]);
    w.w = pkrtz_u(src[3 * HW_], src[3 * HW_ + dn]);
    ws[i] = w;
}

// ---- Pass 2: main blender — 256 thr/block.
// __launch_bounds__(256, 4): 2nd arg is min waves/EU -> <=128 VGPR.
// The previous (256, 8) forced a <=64 VGPR cap; the 2-slot PState pipeline
// (16 uint4 of load data) cannot fit and spills to scratch (~410 MB round
// trip across the dispatch = the dominant cost). 16 waves/CU is ample TLP
// for L2-resident gathers. ----
__global__ __launch_bounds__(256, 4) void blender_kernel(
    const uint4* __restrict__ wsb,     // [B,H,W] f16 pair-duplicated bases
    const float* __restrict__ boxes,   // [B,P,4]
    const float* __restrict__ attn,    // [B,P,K,A,A]
    float* __restrict__ out)           // [B,P,PS,PS]
{
    const int tid = threadIdx.x;       // 256 threads, 4 waves
    const int bp  = blockIdx.x;
    const int b   = bp >> 9;           // / 512

    __shared__ alignas(16) float  smTile[K_ * A_ * A_]; // attn tile, pre-scaled by log2e
    __shared__ alignas(16) float  smR[A_ * PS_ * K_];   // x-interp attn*log2e, [ay][px][k]
    __shared__ alignas(16) float2 smX[PS_];             // {asint(x0*16), asuint(wx h2)}
    __shared__ alignas(16) float2 smTx[PS_];            // {tx, asint(ix0*4)}
    __shared__ alignas(16) float4 smY[PS_];             // {asint(y0*ROWB), o_dy|(ayo<<16), pk(wy0,wy1), ty}

    const float LOG2E = 1.4426950408889634f;

    // ---- stage attn tile (pre-scaled: lerp is linear, fold log2e here) ----
    const float* ap = attn + (size_t)bp * (K_ * A_ * A_);
    for (int i = tid; i < K_ * A_ * A_; i += 256)
        smTile[i] = __builtin_nontemporal_load(ap + i) * LOG2E;

    // ---- separable tables ----
    const float* bx = boxes + (size_t)bp * 4;
    const float rr = 13.0f / 55.0f;            // (A-1)/(PS-1)

    if (tid < PS_) {                           // x-side
        const int px = tid;
        const float x1 = bx[0] * SCALE_;
        const float x2 = bx[2] * SCALE_;
        const float bw = fmaxf(x2 - x1, 1.0f) * (1.0f / PS_);
        const float sx = x1 + (px + 0.5f) * bw;
        const float vx = (sx > -1.0f && sx < (float)W_) ? 1.0f : 0.0f;
        const float cx = fminf(fmaxf(sx, 0.0f), (float)(W_ - 1));
        const int   x0 = (int)cx;
        const float lx = cx - (float)x0;       // x0==W-1 -> lx==0, dup col absorbs
        float2 v;
        v.x = __int_as_float(x0 * PXB_);
        v.y = __uint_as_float(pkrtz_u((1.0f - lx) * vx, lx * vx));
        smX[px] = v;
        // box-independent x-lerp table for the smR fill
        const float srcx = (float)px * rr;
        const int ix0 = min((int)srcx, A_ - 2);
        float2 t;
        t.x = srcx - (float)ix0;
        t.y = __int_as_float(ix0 * 4);         // byte offset within tile row
        smTx[px] = t;
    } else if (tid >= 64 && tid < 64 + PS_) {  // y-side
        const int py = tid - 64;
        const float y1 = bx[1] * SCALE_;
        const float y2 = bx[3] * SCALE_;
        const float bh = fmaxf(y2 - y1, 1.0f) * (1.0f / PS_);
        const float sy = y1 + (py + 0.5f) * bh;
        const float vy = (sy > -1.0f && sy < (float)H_) ? 1.0f : 0.0f;
        const float cy = fminf(fmaxf(sy, 0.0f), (float)(H_ - 1));
        const int   y0 = (int)cy;
        const int   y1i = min(y0 + 1, H_ - 1);
        const float ly = cy - (float)y0;
        const float wy0 = (1.0f - ly) * vy;
        const float wy1 = ly * vy;
        const float srcy = (float)py * rr;
        const int iy0 = min((int)srcy, A_ - 2);
        const unsigned odp = (unsigned)((y1i - y0) * ROWB_)     // 13 bits
                           | ((unsigned)(iy0 * RROWB_) << 16);  // 14 bits
        float4 v;
        v.x = __int_as_float(y0 * ROWB_);
        v.y = __uint_as_float(odp);
        v.z = __uint_as_float(pkrtz_u(wy0, wy1));
        v.w = srcy - (float)iy0;               // ty, fp32
        smY[py] = v;
    }
    __syncthreads();

    // ---- x-interp attn -> smR[ay][px][k]: 784 items, k-vectorized body ----
    for (int i = tid; i < A_ * PS_; i += 256) {             // i = ay*56 + px
        const int ay = (int)(((unsigned)i * 37450u) >> 21); // i/56
        const int px = i - ay * PS_;
        const float2 T = smTx[px];
        const float tx = T.x;
        const int  ixo = __float_as_int(T.y);
        const float* t0 = (const float*)((const char*)smTile + ay * (A_ * 4) + ixo);
        const float* t1 = t0 + A_ * A_;
        const float* t2 = t0 + 2 * A_ * A_;
        const float* t3 = t0 + 3 * A_ * A_;
        float4 o;
        o.x = fmaf(tx, t0[1] - t0[0], t0[0]);
        o.y = fmaf(tx, t1[1] - t1[0], t1[0]);
        o.z = fmaf(tx, t2[1] - t2[0], t2[0]);
        o.w = fmaf(tx, t3[1] - t3[0], t3[0]);
        *(float4*)&smR[i * K_] = o;
    }
    __syncthreads();

    // ---- main loop: idx = tid + 256*t, t = 0..11 (+64 tail); 2-slot pipeline ----
    const char* fb = (const char*)wsb + (size_t)b * PLB_;
    float* outp = out + (size_t)bp * (PS_ * PS_);
    const char* smRc = (const char*)smR;

    // initial px/py for idx = tid  (py = idx/56 via magic, px = rem)
    int py = (int)(((unsigned)tid * 37450u) >> 21);
    int px = tid - py * PS_;

    struct PState {
        uint4 q0, q1;
        unsigned wxu, wyu;
        float ty;
        int   ayo, pxo;
    };

    // issue for current (px,py), then advance (px,py) by 256 linear
    auto issue = [&](PState& S) {
        const int pyc = min(py, PS_ - 1);      // clamp: speculative tail prefetch
        const float2 X = smX[px];
        const float4 Y = smY[pyc];
        const unsigned w1 = __float_as_uint(Y.y);
        const unsigned o0 = (unsigned)__float_as_int(Y.x) + (unsigned)__float_as_int(X.x);
        const unsigned o1 = o0 + (w1 & 0xffffu);
        S.q0 = ld16(fb + o0);
        S.q1 = ld16(fb + o1);
        S.wxu = __float_as_uint(X.y);
        S.wyu = __float_as_uint(Y.z);
        S.ty  = Y.w;
        S.ayo = (int)(w1 >> 16);
        S.pxo = px << 4;
        px += 32; py += 4;
        if (px >= PS_) { px -= PS_; py += 1; }
    };

    auto compute = [&](const PState& S) -> float {
        const h2 wx  = u2h(S.wxu);
        const h2 wyp = u2h(S.wyu);             // {wy0, wy1}
        const h2 wy0b = {wyp.x, wyp.x};        // op_sel broadcast
        const h2 wy1b = {wyp.y, wyp.y};
        const h2 wxy0 = wx * wy0b;             // v_pk_mul_f16
        const h2 wxy1 = wx * wy1b;
        const float v0 = dot2(u2h(S.q1.x), wxy1, dot2(u2h(S.q0.x), wxy0, 0.0f));
        const float v1 = dot2(u2h(S.q1.y), wxy1, dot2(u2h(S.q0.y), wxy0, 0.0f));
        const float v2 = dot2(u2h(S.q1.z), wxy1, dot2(u2h(S.q0.z), wxy0, 0.0f));
        const float v3 = dot2(u2h(S.q1.w), wxy1, dot2(u2h(S.q0.w), wxy0, 0.0f));

        const char* rb = smRc + S.pxo + S.ayo;
        const float4 a0v = *(const float4*)(rb);
        const float4 a1v = *(const float4*)(rb + RROWB_);
        const float ty = S.ty;
        const float e0 = EXP2F(fmaf(ty, a1v.x - a0v.x, a0v.x));
        const float e1 = EXP2F(fmaf(ty, a1v.y - a0v.y, a0v.y));
        const float e2 = EXP2F(fmaf(ty, a1v.z - a0v.z, a0v.z));
        const float e3 = EXP2F(fmaf(ty, a1v.w - a0v.w, a0v.w));

        const float s = (e0 + e1) + (e2 + e3);
        float acc = e0 * v0;
        acc = fmaf(e1, v1, acc);
        acc = fmaf(e2, v2, acc);
        acc = fmaf(e3, v3, acc);
        return acc * __builtin_amdgcn_rcpf(s);
    };

    PState SA, SB;
    issue(SA);
    #pragma unroll
    for (int g = 0; g < 12; g += 2) {
        issue(SB);
        __builtin_nontemporal_store(compute(SA), outp + tid + 256 * g);
        issue(SA);                              // g=10 -> prefetches tail (clamped)
        __builtin_nontemporal_store(compute(SB), outp + tid + 256 * (g + 1));
    }
    if (tid < 64)                               // tail: idx = 3072 + tid
        __builtin_nontemporal_store(compute(SA), outp + tid + 256 * 12);
}

extern "C" void kernel_launch(void* const* d_in, const int* in_sizes, int n_in,
                              void* d_out, int out_size, void* d_ws, size_t ws_size,
                              hipStream_t stream) {
    const float* bases = (const float*)d_in[0];  // [B,K,H,W]
    const float* boxes = (const float*)d_in[1];  // [B,P,4]
    const float* attn  = (const float*)d_in[2];  // [B,P,K,A,A]
    float* out = (float*)d_out;                  // [B,P,PS,PS]
    uint4* wsb = (uint4*)d_ws;                   // 268800 * 16 B = 4.3 MB scratch

    transpose_bases<<<dim3((B_ * HW_ + 255) / 256), dim3(256), 0, stream>>>(bases, wsb);
    blender_kernel<<<dim3(B_ * P_), dim3(256), 0, stream>>>(wsb, boxes, attn, out);
}